// Round 1
// baseline (190.491 us; speedup 1.0000x reference)
//
#include <hip/hip_runtime.h>

#define T_STEPS 128
#define B_TOTAL 65536
#define BLOCK 256
#define NBLOCKS (B_TOTAL / BLOCK)

__device__ __forceinline__ float fast_sigmoid(float x) {
    return 1.0f / (1.0f + __expf(-x));
}
__device__ __forceinline__ float fast_tanh(float x) {
    // tanh(x) = 1 - 2/(exp(2x)+1); saturates correctly via inf/0
    return 1.0f - 2.0f / (__expf(2.0f * x) + 1.0f);
}

__global__ __launch_bounds__(BLOCK) void lstm_nll_main(
    const float* __restrict__ x,       // (B, T, 3)
    const float* __restrict__ h0,      // (B)
    const float* __restrict__ c0,      // (B)
    const float* __restrict__ target,  // (B, 3)
    const float* __restrict__ W_ih,    // (4,3)
    const float* __restrict__ W_hh,    // (4,1)
    const float* __restrict__ b_ih,    // (4)
    const float* __restrict__ b_hh,    // (4)
    const float* __restrict__ W_mean,  // (3,128)
    const float* __restrict__ b_mean,  // (3)
    const float* __restrict__ W_var,   // (6,128)
    const float* __restrict__ b_var,   // (6)
    float* __restrict__ partial)       // (NBLOCKS)
{
    // wpack[t*12 + k]: k=0..2 -> W_mean[:,t], k=3..8 -> W_var[:,t], k=9..11 pad
    __shared__ float wpack[T_STEPS * 12];
    __shared__ float wavesum[BLOCK / 64];

    const int tid = threadIdx.x;
    for (int idx = tid; idx < T_STEPS * 12; idx += BLOCK) {
        const int t = idx / 12;
        const int k = idx - t * 12;
        float v = 0.0f;
        if (k < 3)      v = W_mean[k * T_STEPS + t];
        else if (k < 9) v = W_var[(k - 3) * T_STEPS + t];
        wpack[idx] = v;
    }
    __syncthreads();

    const int b = blockIdx.x * BLOCK + tid;
    const float* xb = x + (size_t)b * (T_STEPS * 3);
    const float4* xb4 = (const float4*)xb;

    // ---- rotation matrix from rows T-1, T-2, T-3 ----
    const float v1x = xb[127*3+0], v1y = xb[127*3+1], v1z = xb[127*3+2];
    const float v2x = xb[126*3+0], v2y = xb[126*3+1], v2z = xb[126*3+2];
    const float v3x = xb[125*3+0], v3y = xb[125*3+1], v3z = xb[125*3+2];

    const float inv1 = rsqrtf(v1x*v1x + v1y*v1y + v1z*v1z);
    const float b1x = v1x*inv1, b1y = v1y*inv1, b1z = v1z*inv1;
    const float dp  = v2x*b1x + v2y*b1y + v2z*b1z;
    const float a2x = v2x - dp*b1x, a2y = v2y - dp*b1y, a2z = v2z - dp*b1z;
    const float inv2 = rsqrtf(a2x*a2x + a2y*a2y + a2z*a2z);
    const float b2x = a2x*inv2, b2y = a2y*inv2, b2z = a2z*inv2;
    float b3x = b1y*b2z - b1z*b2y;
    float b3y = b1z*b2x - b1x*b2z;
    float b3z = b1x*b2y - b1y*b2x;
    const float sgn = (v3x*b3x + v3y*b3y + v3z*b3z) > 0.0f ? 1.0f : -1.0f;
    b3x *= sgn; b3y *= sgn; b3z *= sgn;

    // ---- gate weights (wave-uniform loads) ----
    const float wi00 = W_ih[0], wi01 = W_ih[1],  wi02 = W_ih[2];
    const float wi10 = W_ih[3], wi11 = W_ih[4],  wi12 = W_ih[5];
    const float wi20 = W_ih[6], wi21 = W_ih[7],  wi22 = W_ih[8];
    const float wi30 = W_ih[9], wi31 = W_ih[10], wi32 = W_ih[11];
    const float wh0 = W_hh[0], wh1 = W_hh[1], wh2 = W_hh[2], wh3 = W_hh[3];
    const float bg0 = b_ih[0] + b_hh[0];
    const float bg1 = b_ih[1] + b_hh[1];
    const float bg2 = b_ih[2] + b_hh[2];
    const float bg3 = b_ih[3] + b_hh[3];

    float h = h0[b];
    float c = c0[b];
    float m0 = 0.f, m1 = 0.f, m2 = 0.f;
    float e0 = 0.f, e1 = 0.f, e2 = 0.f, e3 = 0.f, e4 = 0.f, e5 = 0.f;

    // double-buffered chunks: 8 rows = 24 floats = 6 aligned float4
    float4 pre[6];
    #pragma unroll
    for (int q = 0; q < 6; ++q) pre[q] = xb4[q];

    for (int tc = 0; tc < 16; ++tc) {
        float cur[24];
        #pragma unroll
        for (int q = 0; q < 6; ++q) {
            cur[q*4+0] = pre[q].x; cur[q*4+1] = pre[q].y;
            cur[q*4+2] = pre[q].z; cur[q*4+3] = pre[q].w;
        }
        if (tc < 15) {
            #pragma unroll
            for (int q = 0; q < 6; ++q) pre[q] = xb4[(tc + 1) * 6 + q];
        }
        #pragma unroll
        for (int r = 0; r < 8; ++r) {
            const float xx = cur[r*3+0], xy = cur[r*3+1], xz = cur[r*3+2];
            // rot = R^T x  (columns b1, b2, sgn*b3)
            const float r0 = b1x*xx + b1y*xy + b1z*xz;
            const float r1 = b2x*xx + b2y*xy + b2z*xz;
            const float r2 = b3x*xx + b3y*xy + b3z*xz;
            const float gi = wi00*r0 + wi01*r1 + wi02*r2 + wh0*h + bg0;
            const float gf = wi10*r0 + wi11*r1 + wi12*r2 + wh1*h + bg1;
            const float gc = wi20*r0 + wi21*r1 + wi22*r2 + wh2*h + bg2;
            const float go = wi30*r0 + wi31*r1 + wi32*r2 + wh3*h + bg3;
            const float ig = fast_sigmoid(gi);
            const float fg = fast_sigmoid(gf);
            const float tg = fast_tanh(gc);
            const float og = fast_sigmoid(go);
            c = fg * c + ig * tg;
            h = og * fast_tanh(c);
            // on-the-fly feat projections
            const int t = tc * 8 + r;
            const float* wp = &wpack[t * 12];
            m0 += wp[0]*h; m1 += wp[1]*h; m2 += wp[2]*h;
            e0 += wp[3]*h; e1 += wp[4]*h; e2 += wp[5]*h;
            e3 += wp[6]*h; e4 += wp[7]*h; e5 += wp[8]*h;
        }
    }

    // ---- epilogue: NLL for this batch element ----
    m0 += b_mean[0]; m1 += b_mean[1]; m2 += b_mean[2];
    e0 += b_var[0]; e1 += b_var[1]; e2 += b_var[2];
    e3 += b_var[3]; e4 += b_var[4]; e5 += b_var[5];

    const float dv0 = __expf(e3), dv1 = __expf(e4), dv2 = __expf(e5);

    const float t0 = target[b*3+0], t1 = target[b*3+1], t2 = target[b*3+2];
    const float rt0 = b1x*t0 + b1y*t1 + b1z*t2;
    const float rt1 = b2x*t0 + b2y*t1 + b2z*t2;
    const float rt2 = b3x*t0 + b3y*t1 + b3z*t2;

    const float d0 = m0 - rt0, d1 = m1 - rt1, d2 = m2 - rt2;
    // sigma = L D L^T, L unit-lower with (e0,e1,e2); quad = ||D^-1/2 L^-1 d||^2
    const float y0 = d0;
    const float y1 = d1 - e0 * y0;
    const float y2 = d2 - e1 * y0 - e2 * y1;
    const float quad = y0*y0/dv0 + y1*y1/dv1 + y2*y2/dv2;

    float contrib = 0.5f * (dv0 + dv1 + dv2) + 0.5f * quad;  // = -logprob_b

    // ---- block reduction ----
    #pragma unroll
    for (int off = 32; off > 0; off >>= 1)
        contrib += __shfl_down(contrib, off, 64);
    const int lane = tid & 63, wid = tid >> 6;
    if (lane == 0) wavesum[wid] = contrib;
    __syncthreads();
    if (tid == 0) {
        float s = 0.f;
        #pragma unroll
        for (int w = 0; w < BLOCK / 64; ++w) s += wavesum[w];
        partial[blockIdx.x] = s;
    }
}

__global__ __launch_bounds__(256) void lstm_nll_finalize(
    const float* __restrict__ partial, float* __restrict__ out, int n)
{
    const int tid = threadIdx.x;
    float s = (tid < n) ? partial[tid] : 0.0f;
    #pragma unroll
    for (int off = 32; off > 0; off >>= 1)
        s += __shfl_down(s, off, 64);
    __shared__ float wavesum[4];
    const int lane = tid & 63, wid = tid >> 6;
    if (lane == 0) wavesum[wid] = s;
    __syncthreads();
    if (tid == 0) {
        out[0] = (wavesum[0] + wavesum[1] + wavesum[2] + wavesum[3]) *
                 (1.0f / (float)B_TOTAL);
    }
}

extern "C" void kernel_launch(void* const* d_in, const int* in_sizes, int n_in,
                              void* d_out, int out_size, void* d_ws, size_t ws_size,
                              hipStream_t stream) {
    const float* x      = (const float*)d_in[0];   // history_input (B,1,T,F)
    const float* h0     = (const float*)d_in[1];   // (1,B,H)
    const float* c0     = (const float*)d_in[2];   // (1,B,H)
    const float* target = (const float*)d_in[3];   // (B,1,F)
    const float* W_ih   = (const float*)d_in[4];
    const float* W_hh   = (const float*)d_in[5];
    const float* b_ih   = (const float*)d_in[6];
    const float* b_hh   = (const float*)d_in[7];
    const float* W_mean = (const float*)d_in[8];
    const float* b_mean = (const float*)d_in[9];
    const float* W_var  = (const float*)d_in[10];
    const float* b_var  = (const float*)d_in[11];

    float* partial = (float*)d_ws;  // NBLOCKS floats

    lstm_nll_main<<<NBLOCKS, BLOCK, 0, stream>>>(
        x, h0, c0, target, W_ih, W_hh, b_ih, b_hh,
        W_mean, b_mean, W_var, b_var, partial);
    lstm_nll_finalize<<<1, 256, 0, stream>>>(partial, (float*)d_out, NBLOCKS);
}

// Round 2
// 183.778 us; speedup vs baseline: 1.0365x; 1.0365x over previous
//
#include <hip/hip_runtime.h>

#define T_STEPS 128
#define B_TOTAL 65536
#define BLOCK 256
#define NBLOCKS (B_TOTAL / BLOCK)
#define CH 16                  // timesteps per staged chunk
#define NCH (T_STEPS / CH)     // 8 chunks
#define ROWF (CH * 3)          // 48 floats per row per chunk
#define RSTRIDE (ROWF + 1)     // 49 (odd) -> conflict-free per-lane LDS reads
#define FPT 12                 // float4 loads/thread/chunk = 256*48/(4*256)

__device__ __forceinline__ float fast_sigmoid(float x) {
    return 1.0f / (1.0f + __expf(-x));
}
__device__ __forceinline__ float fast_tanh(float x) {
    return 1.0f - 2.0f / (__expf(2.0f * x) + 1.0f);
}

__global__ __launch_bounds__(BLOCK, 1) void lstm_nll_main(
    const float* __restrict__ x,       // (B, T, 3)
    const float* __restrict__ h0,      // (B)
    const float* __restrict__ c0,      // (B)
    const float* __restrict__ target,  // (B, 3)
    const float* __restrict__ W_ih,    // (4,3)
    const float* __restrict__ W_hh,    // (4,1)
    const float* __restrict__ b_ih,    // (4)
    const float* __restrict__ b_hh,    // (4)
    const float* __restrict__ W_mean,  // (3,128)
    const float* __restrict__ b_mean,  // (3)
    const float* __restrict__ W_var,   // (6,128)
    const float* __restrict__ b_var,   // (6)
    float* __restrict__ partial)       // (NBLOCKS)
{
    __shared__ float  lds_x[BLOCK * RSTRIDE];   // 50176 B
    __shared__ float4 wpack4[T_STEPS * 3];      // 6144 B
    __shared__ float  wavesum[BLOCK / 64];

    const int tid = threadIdx.x;

    // pack projection weights: per t, 3 float4: {m0,m1,m2,e0},{e1,e2,e3,e4},{e5,0,0,0}
    for (int idx = tid; idx < T_STEPS * 3; idx += BLOCK) {
        const int t = idx / 3;
        const int k = idx - t * 3;
        float4 v;
        if (k == 0)      v = make_float4(W_mean[0*T_STEPS+t], W_mean[1*T_STEPS+t],
                                         W_mean[2*T_STEPS+t], W_var[0*T_STEPS+t]);
        else if (k == 1) v = make_float4(W_var[1*T_STEPS+t], W_var[2*T_STEPS+t],
                                         W_var[3*T_STEPS+t], W_var[4*T_STEPS+t]);
        else             v = make_float4(W_var[5*T_STEPS+t], 0.f, 0.f, 0.f);
        wpack4[idx] = v;
    }

    const int b = blockIdx.x * BLOCK + tid;
    const float* xb = x + (size_t)b * (T_STEPS * 3);

    // ---- rotation from rows 127,126,125 (small prologue, latency paid once) ----
    const float v1x = xb[127*3+0], v1y = xb[127*3+1], v1z = xb[127*3+2];
    const float v2x = xb[126*3+0], v2y = xb[126*3+1], v2z = xb[126*3+2];
    const float v3x = xb[125*3+0], v3y = xb[125*3+1], v3z = xb[125*3+2];

    const float inv1 = rsqrtf(v1x*v1x + v1y*v1y + v1z*v1z);
    const float b1x = v1x*inv1, b1y = v1y*inv1, b1z = v1z*inv1;
    const float dp  = v2x*b1x + v2y*b1y + v2z*b1z;
    const float a2x = v2x - dp*b1x, a2y = v2y - dp*b1y, a2z = v2z - dp*b1z;
    const float inv2 = rsqrtf(a2x*a2x + a2y*a2y + a2z*a2z);
    const float b2x = a2x*inv2, b2y = a2y*inv2, b2z = a2z*inv2;
    float b3x = b1y*b2z - b1z*b2y;
    float b3y = b1z*b2x - b1x*b2z;
    float b3z = b1x*b2y - b1y*b2x;
    const float sgn = (v3x*b3x + v3y*b3y + v3z*b3z) > 0.0f ? 1.0f : -1.0f;
    b3x *= sgn; b3y *= sgn; b3z *= sgn;

    // ---- gate weights folded with rotation: wf_g = wi_g0*b1 + wi_g1*b2 + wi_g2*b3 ----
    const float wi00 = W_ih[0], wi01 = W_ih[1],  wi02 = W_ih[2];
    const float wi10 = W_ih[3], wi11 = W_ih[4],  wi12 = W_ih[5];
    const float wi20 = W_ih[6], wi21 = W_ih[7],  wi22 = W_ih[8];
    const float wi30 = W_ih[9], wi31 = W_ih[10], wi32 = W_ih[11];
    const float wf0x = wi00*b1x + wi01*b2x + wi02*b3x;
    const float wf0y = wi00*b1y + wi01*b2y + wi02*b3y;
    const float wf0z = wi00*b1z + wi01*b2z + wi02*b3z;
    const float wf1x = wi10*b1x + wi11*b2x + wi12*b3x;
    const float wf1y = wi10*b1y + wi11*b2y + wi12*b3y;
    const float wf1z = wi10*b1z + wi11*b2z + wi12*b3z;
    const float wf2x = wi20*b1x + wi21*b2x + wi22*b3x;
    const float wf2y = wi20*b1y + wi21*b2y + wi22*b3y;
    const float wf2z = wi20*b1z + wi21*b2z + wi22*b3z;
    const float wf3x = wi30*b1x + wi31*b2x + wi32*b3x;
    const float wf3y = wi30*b1y + wi31*b2y + wi32*b3y;
    const float wf3z = wi30*b1z + wi31*b2z + wi32*b3z;
    const float wh0 = W_hh[0], wh1 = W_hh[1], wh2 = W_hh[2], wh3 = W_hh[3];
    const float bg0 = b_ih[0] + b_hh[0];
    const float bg1 = b_ih[1] + b_hh[1];
    const float bg2 = b_ih[2] + b_hh[2];
    const float bg3 = b_ih[3] + b_hh[3];

    float h = h0[b];
    float c = c0[b];
    float m0 = 0.f, m1 = 0.f, m2 = 0.f;
    float e0 = 0.f, e1 = 0.f, e2 = 0.f, e3 = 0.f, e4 = 0.f, e5 = 0.f;

    // ---- coalesced staging plan: chunk = 256 rows x CH steps ----
    // flat float4 index within chunk: f = j*BLOCK + tid ; row r = f/12, col c = f%12
    const float4* xg4 = (const float4*)(x + (size_t)blockIdx.x * BLOCK * (T_STEPS * 3));
    int ldsaddr[FPT];
    int gidx[FPT];
    #pragma unroll
    for (int j = 0; j < FPT; ++j) {
        const int f = j * BLOCK + tid;
        const int r = f / FPT;
        const int cc = f - r * FPT;
        ldsaddr[j] = r * RSTRIDE + cc * 4;
        gidx[j]    = r * (T_STEPS * 3 / 4) + cc;   // r*96 + c (chunk base added later)
    }

    float4 pre[FPT];
    #pragma unroll
    for (int j = 0; j < FPT; ++j) pre[j] = xg4[gidx[j]];

    const float* rowp = &lds_x[tid * RSTRIDE];

    for (int tc = 0; tc < NCH; ++tc) {
        __syncthreads();   // previous chunk's LDS reads done (also covers wpack4 pack)
        #pragma unroll
        for (int j = 0; j < FPT; ++j) {
            lds_x[ldsaddr[j] + 0] = pre[j].x;
            lds_x[ldsaddr[j] + 1] = pre[j].y;
            lds_x[ldsaddr[j] + 2] = pre[j].z;
            lds_x[ldsaddr[j] + 3] = pre[j].w;
        }
        __syncthreads();
        if (tc + 1 < NCH) {
            const int cb = (tc + 1) * FPT;
            #pragma unroll
            for (int j = 0; j < FPT; ++j) pre[j] = xg4[gidx[j] + cb];
        }
        #pragma unroll
        for (int s = 0; s < CH; ++s) {
            const float xx = rowp[s*3+0], xy = rowp[s*3+1], xz = rowp[s*3+2];
            const float gi = wf0x*xx + wf0y*xy + wf0z*xz + wh0*h + bg0;
            const float gf = wf1x*xx + wf1y*xy + wf1z*xz + wh1*h + bg1;
            const float gc = wf2x*xx + wf2y*xy + wf2z*xz + wh2*h + bg2;
            const float go = wf3x*xx + wf3y*xy + wf3z*xz + wh3*h + bg3;
            const float ig = fast_sigmoid(gi);
            const float fg = fast_sigmoid(gf);
            const float tg = fast_tanh(gc);
            const float og = fast_sigmoid(go);
            c = fg * c + ig * tg;
            h = og * fast_tanh(c);
            const int t = tc * CH + s;
            const float4 w0 = wpack4[t*3+0];
            const float4 w1 = wpack4[t*3+1];
            const float4 w2 = wpack4[t*3+2];
            m0 += w0.x*h; m1 += w0.y*h; m2 += w0.z*h;
            e0 += w0.w*h; e1 += w1.x*h; e2 += w1.y*h;
            e3 += w1.z*h; e4 += w1.w*h; e5 += w2.x*h;
        }
    }

    // ---- epilogue: NLL ----
    m0 += b_mean[0]; m1 += b_mean[1]; m2 += b_mean[2];
    e0 += b_var[0]; e1 += b_var[1]; e2 += b_var[2];
    e3 += b_var[3]; e4 += b_var[4]; e5 += b_var[5];

    const float dv0 = __expf(e3), dv1 = __expf(e4), dv2 = __expf(e5);

    const float t0 = target[b*3+0], t1 = target[b*3+1], t2 = target[b*3+2];
    const float rt0 = b1x*t0 + b1y*t1 + b1z*t2;
    const float rt1 = b2x*t0 + b2y*t1 + b2z*t2;
    const float rt2 = b3x*t0 + b3y*t1 + b3z*t2;

    const float d0 = m0 - rt0, d1 = m1 - rt1, d2 = m2 - rt2;
    const float y0 = d0;
    const float y1 = d1 - e0 * y0;
    const float y2 = d2 - e1 * y0 - e2 * y1;
    const float quad = y0*y0/dv0 + y1*y1/dv1 + y2*y2/dv2;

    float contrib = 0.5f * (dv0 + dv1 + dv2) + 0.5f * quad;

    #pragma unroll
    for (int off = 32; off > 0; off >>= 1)
        contrib += __shfl_down(contrib, off, 64);
    const int lane = tid & 63, wid = tid >> 6;
    if (lane == 0) wavesum[wid] = contrib;
    __syncthreads();
    if (tid == 0) {
        float s = 0.f;
        #pragma unroll
        for (int w = 0; w < BLOCK / 64; ++w) s += wavesum[w];
        partial[blockIdx.x] = s;
    }
}

__global__ __launch_bounds__(256) void lstm_nll_finalize(
    const float* __restrict__ partial, float* __restrict__ out, int n)
{
    const int tid = threadIdx.x;
    float s = (tid < n) ? partial[tid] : 0.0f;
    #pragma unroll
    for (int off = 32; off > 0; off >>= 1)
        s += __shfl_down(s, off, 64);
    __shared__ float wavesum[4];
    const int lane = tid & 63, wid = tid >> 6;
    if (lane == 0) wavesum[wid] = s;
    __syncthreads();
    if (tid == 0) {
        out[0] = (wavesum[0] + wavesum[1] + wavesum[2] + wavesum[3]) *
                 (1.0f / (float)B_TOTAL);
    }
}

extern "C" void kernel_launch(void* const* d_in, const int* in_sizes, int n_in,
                              void* d_out, int out_size, void* d_ws, size_t ws_size,
                              hipStream_t stream) {
    const float* x      = (const float*)d_in[0];
    const float* h0     = (const float*)d_in[1];
    const float* c0     = (const float*)d_in[2];
    const float* target = (const float*)d_in[3];
    const float* W_ih   = (const float*)d_in[4];
    const float* W_hh   = (const float*)d_in[5];
    const float* b_ih   = (const float*)d_in[6];
    const float* b_hh   = (const float*)d_in[7];
    const float* W_mean = (const float*)d_in[8];
    const float* b_mean = (const float*)d_in[9];
    const float* W_var  = (const float*)d_in[10];
    const float* b_var  = (const float*)d_in[11];

    float* partial = (float*)d_ws;

    lstm_nll_main<<<NBLOCKS, BLOCK, 0, stream>>>(
        x, h0, c0, target, W_ih, W_hh, b_ih, b_hh,
        W_mean, b_mean, W_var, b_var, partial);
    lstm_nll_finalize<<<1, 256, 0, stream>>>(partial, (float*)d_out, NBLOCKS);
}

// Round 3
// 178.693 us; speedup vs baseline: 1.0660x; 1.0285x over previous
//
#include <hip/hip_runtime.h>

#define T_STEPS 128
#define B_TOTAL 65536
#define BLOCK 256
#define NBLOCKS (B_TOTAL / BLOCK)
#define CH 16                  // timesteps per staged chunk
#define NCH (T_STEPS / CH)     // 8 chunks
#define ROWF (CH * 3)          // 48 floats per row per chunk
#define RSTRIDE (ROWF + 1)     // 49 (odd) -> conflict-free per-lane LDS reads
#define FPT 12                 // float4 loads/thread/chunk

#define LOG2E 1.44269504088896f

__device__ __forceinline__ float fast_rcp(float x) {
    return __builtin_amdgcn_rcpf(x);
}
__device__ __forceinline__ float fast_sigmoid(float x) {
    // 1/(1+e^-x) : v_mul + v_exp + v_add + v_rcp
    return fast_rcp(1.0f + __builtin_amdgcn_exp2f(-x * LOG2E));
}
__device__ __forceinline__ float fast_tanh(float x) {
    // 1 - 2/(e^{2x}+1)
    return __builtin_fmaf(-2.0f,
        fast_rcp(1.0f + __builtin_amdgcn_exp2f(x * (2.0f * LOG2E))), 1.0f);
}

__global__ __launch_bounds__(BLOCK, 1) void lstm_nll_main(
    const float* __restrict__ x,       // (B, T, 3)
    const float* __restrict__ h0,      // (B)
    const float* __restrict__ c0,      // (B)
    const float* __restrict__ target,  // (B, 3)
    const float* __restrict__ W_ih,    // (4,3)
    const float* __restrict__ W_hh,    // (4,1)
    const float* __restrict__ b_ih,    // (4)
    const float* __restrict__ b_hh,    // (4)
    const float* __restrict__ W_mean,  // (3,128)
    const float* __restrict__ b_mean,  // (3)
    const float* __restrict__ W_var,   // (6,128)
    const float* __restrict__ b_var,   // (6)
    float* __restrict__ partial)       // (NBLOCKS)
{
    __shared__ float  lds_x[BLOCK * RSTRIDE];   // 50176 B
    __shared__ float4 wpack4[T_STEPS * 3];      // 6144 B
    __shared__ float  wavesum[BLOCK / 64];

    const int tid = threadIdx.x;

    // pack projection weights: per t: {m0,m1,m2,e0},{e1,e2,e3,e4},{e5,0,0,0}
    for (int idx = tid; idx < T_STEPS * 3; idx += BLOCK) {
        const int t = idx / 3;
        const int k = idx - t * 3;
        float4 v;
        if (k == 0)      v = make_float4(W_mean[0*T_STEPS+t], W_mean[1*T_STEPS+t],
                                         W_mean[2*T_STEPS+t], W_var[0*T_STEPS+t]);
        else if (k == 1) v = make_float4(W_var[1*T_STEPS+t], W_var[2*T_STEPS+t],
                                         W_var[3*T_STEPS+t], W_var[4*T_STEPS+t]);
        else             v = make_float4(W_var[5*T_STEPS+t], 0.f, 0.f, 0.f);
        wpack4[idx] = v;
    }

    const int b = blockIdx.x * BLOCK + tid;
    const float* xb = x + (size_t)b * (T_STEPS * 3);

    // ---- rotation from rows 127,126,125 ----
    const float v1x = xb[127*3+0], v1y = xb[127*3+1], v1z = xb[127*3+2];
    const float v2x = xb[126*3+0], v2y = xb[126*3+1], v2z = xb[126*3+2];
    const float v3x = xb[125*3+0], v3y = xb[125*3+1], v3z = xb[125*3+2];

    const float inv1 = rsqrtf(v1x*v1x + v1y*v1y + v1z*v1z);
    const float b1x = v1x*inv1, b1y = v1y*inv1, b1z = v1z*inv1;
    const float dp  = v2x*b1x + v2y*b1y + v2z*b1z;
    const float a2x = v2x - dp*b1x, a2y = v2y - dp*b1y, a2z = v2z - dp*b1z;
    const float inv2 = rsqrtf(a2x*a2x + a2y*a2y + a2z*a2z);
    const float b2x = a2x*inv2, b2y = a2y*inv2, b2z = a2z*inv2;
    float b3x = b1y*b2z - b1z*b2y;
    float b3y = b1z*b2x - b1x*b2z;
    float b3z = b1x*b2y - b1y*b2x;
    const float sgn = (v3x*b3x + v3y*b3y + v3z*b3z) > 0.0f ? 1.0f : -1.0f;
    b3x *= sgn; b3y *= sgn; b3z *= sgn;

    // ---- gate weights folded with rotation ----
    const float wi00 = W_ih[0], wi01 = W_ih[1],  wi02 = W_ih[2];
    const float wi10 = W_ih[3], wi11 = W_ih[4],  wi12 = W_ih[5];
    const float wi20 = W_ih[6], wi21 = W_ih[7],  wi22 = W_ih[8];
    const float wi30 = W_ih[9], wi31 = W_ih[10], wi32 = W_ih[11];
    const float wf0x = wi00*b1x + wi01*b2x + wi02*b3x;
    const float wf0y = wi00*b1y + wi01*b2y + wi02*b3y;
    const float wf0z = wi00*b1z + wi01*b2z + wi02*b3z;
    const float wf1x = wi10*b1x + wi11*b2x + wi12*b3x;
    const float wf1y = wi10*b1y + wi11*b2y + wi12*b3y;
    const float wf1z = wi10*b1z + wi11*b2z + wi12*b3z;
    const float wf2x = wi20*b1x + wi21*b2x + wi22*b3x;
    const float wf2y = wi20*b1y + wi21*b2y + wi22*b3y;
    const float wf2z = wi20*b1z + wi21*b2z + wi22*b3z;
    const float wf3x = wi30*b1x + wi31*b2x + wi32*b3x;
    const float wf3y = wi30*b1y + wi31*b2y + wi32*b3y;
    const float wf3z = wi30*b1z + wi31*b2z + wi32*b3z;
    const float wh0 = W_hh[0], wh1 = W_hh[1], wh2 = W_hh[2], wh3 = W_hh[3];
    const float bg0 = b_ih[0] + b_hh[0];
    const float bg1 = b_ih[1] + b_hh[1];
    const float bg2 = b_ih[2] + b_hh[2];
    const float bg3 = b_ih[3] + b_hh[3];

    float h = h0[b];
    float c = c0[b];
    float m0 = 0.f, m1 = 0.f, m2 = 0.f;
    float e0 = 0.f, e1 = 0.f, e2 = 0.f, e3 = 0.f, e4 = 0.f, e5 = 0.f;

    // ---- coalesced staging plan ----
    const float4* xg4 = (const float4*)(x + (size_t)blockIdx.x * BLOCK * (T_STEPS * 3));
    int ldsaddr[FPT];
    int gidx[FPT];
    #pragma unroll
    for (int j = 0; j < FPT; ++j) {
        const int f = j * BLOCK + tid;
        const int r = f / FPT;
        const int cc = f - r * FPT;
        ldsaddr[j] = r * RSTRIDE + cc * 4;
        gidx[j]    = r * (T_STEPS * 3 / 4) + cc;
    }

    float4 pre[FPT];
    #pragma unroll
    for (int j = 0; j < FPT; ++j) pre[j] = xg4[gidx[j]];

    const float* rowp = &lds_x[tid * RSTRIDE];

    for (int tc = 0; tc < NCH; ++tc) {
        __syncthreads();
        #pragma unroll
        for (int j = 0; j < FPT; ++j) {
            lds_x[ldsaddr[j] + 0] = pre[j].x;
            lds_x[ldsaddr[j] + 1] = pre[j].y;
            lds_x[ldsaddr[j] + 2] = pre[j].z;
            lds_x[ldsaddr[j] + 3] = pre[j].w;
        }
        __syncthreads();
        if (tc + 1 < NCH) {
            const int cb = (tc + 1) * FPT;
            #pragma unroll
            for (int j = 0; j < FPT; ++j) pre[j] = xg4[gidx[j] + cb];
        }

        // ---- phase A: serial recurrence only, h values into registers ----
        float hbuf[CH];
        #pragma unroll
        for (int s = 0; s < CH; ++s) {
            const float xx = rowp[s*3+0], xy = rowp[s*3+1], xz = rowp[s*3+2];
            const float gi = wf0x*xx + wf0y*xy + wf0z*xz + wh0*h + bg0;
            const float gf = wf1x*xx + wf1y*xy + wf1z*xz + wh1*h + bg1;
            const float gc = wf2x*xx + wf2y*xy + wf2z*xz + wh2*h + bg2;
            const float go = wf3x*xx + wf3y*xy + wf3z*xz + wh3*h + bg3;
            const float ig = fast_sigmoid(gi);
            const float fg = fast_sigmoid(gf);
            const float tg = fast_tanh(gc);
            const float og = fast_sigmoid(go);
            c = fg * c + ig * tg;
            h = og * fast_tanh(c);
            hbuf[s] = h;
        }
        // ---- phase B: streaming projection accumulate ----
        #pragma unroll
        for (int s = 0; s < CH; ++s) {
            const int t = tc * CH + s;
            const float4 w0 = wpack4[t*3+0];
            const float4 w1 = wpack4[t*3+1];
            const float4 w2 = wpack4[t*3+2];
            const float hv = hbuf[s];
            m0 += w0.x*hv; m1 += w0.y*hv; m2 += w0.z*hv;
            e0 += w0.w*hv; e1 += w1.x*hv; e2 += w1.y*hv;
            e3 += w1.z*hv; e4 += w1.w*hv; e5 += w2.x*hv;
        }
    }

    // ---- epilogue: NLL (division-free) ----
    m0 += b_mean[0]; m1 += b_mean[1]; m2 += b_mean[2];
    e0 += b_var[0]; e1 += b_var[1]; e2 += b_var[2];
    e3 += b_var[3]; e4 += b_var[4]; e5 += b_var[5];

    const float dv0 = __builtin_amdgcn_exp2f(e3 * LOG2E);
    const float dv1 = __builtin_amdgcn_exp2f(e4 * LOG2E);
    const float dv2 = __builtin_amdgcn_exp2f(e5 * LOG2E);

    const float t0 = target[b*3+0], t1 = target[b*3+1], t2 = target[b*3+2];
    const float rt0 = b1x*t0 + b1y*t1 + b1z*t2;
    const float rt1 = b2x*t0 + b2y*t1 + b2z*t2;
    const float rt2 = b3x*t0 + b3y*t1 + b3z*t2;

    const float d0 = m0 - rt0, d1 = m1 - rt1, d2 = m2 - rt2;
    const float y0 = d0;
    const float y1 = d1 - e0 * y0;
    const float y2 = d2 - e1 * y0 - e2 * y1;
    const float quad = y0*y0*fast_rcp(dv0) + y1*y1*fast_rcp(dv1)
                     + y2*y2*fast_rcp(dv2);

    float contrib = 0.5f * (dv0 + dv1 + dv2) + 0.5f * quad;

    #pragma unroll
    for (int off = 32; off > 0; off >>= 1)
        contrib += __shfl_down(contrib, off, 64);
    const int lane = tid & 63, wid = tid >> 6;
    if (lane == 0) wavesum[wid] = contrib;
    __syncthreads();
    if (tid == 0) {
        float s = 0.f;
        #pragma unroll
        for (int w = 0; w < BLOCK / 64; ++w) s += wavesum[w];
        partial[blockIdx.x] = s;
    }
}

__global__ __launch_bounds__(256) void lstm_nll_finalize(
    const float* __restrict__ partial, float* __restrict__ out, int n)
{
    const int tid = threadIdx.x;
    float s = (tid < n) ? partial[tid] : 0.0f;
    #pragma unroll
    for (int off = 32; off > 0; off >>= 1)
        s += __shfl_down(s, off, 64);
    __shared__ float wavesum[4];
    const int lane = tid & 63, wid = tid >> 6;
    if (lane == 0) wavesum[wid] = s;
    __syncthreads();
    if (tid == 0) {
        out[0] = (wavesum[0] + wavesum[1] + wavesum[2] + wavesum[3]) *
                 (1.0f / (float)B_TOTAL);
    }
}

extern "C" void kernel_launch(void* const* d_in, const int* in_sizes, int n_in,
                              void* d_out, int out_size, void* d_ws, size_t ws_size,
                              hipStream_t stream) {
    const float* x      = (const float*)d_in[0];
    const float* h0     = (const float*)d_in[1];
    const float* c0     = (const float*)d_in[2];
    const float* target = (const float*)d_in[3];
    const float* W_ih   = (const float*)d_in[4];
    const float* W_hh   = (const float*)d_in[5];
    const float* b_ih   = (const float*)d_in[6];
    const float* b_hh   = (const float*)d_in[7];
    const float* W_mean = (const float*)d_in[8];
    const float* b_mean = (const float*)d_in[9];
    const float* W_var  = (const float*)d_in[10];
    const float* b_var  = (const float*)d_in[11];

    float* partial = (float*)d_ws;

    lstm_nll_main<<<NBLOCKS, BLOCK, 0, stream>>>(
        x, h0, c0, target, W_ih, W_hh, b_ih, b_hh,
        W_mean, b_mean, W_var, b_var, partial);
    lstm_nll_finalize<<<1, 256, 0, stream>>>(partial, (float*)d_out, NBLOCKS);
}

// Round 4
// 178.482 us; speedup vs baseline: 1.0673x; 1.0012x over previous
//
#include <hip/hip_runtime.h>

#define T_STEPS 128
#define B_TOTAL 65536
#define BLOCK 256
#define NBLOCKS (B_TOTAL / BLOCK)
#define CH 8                   // timesteps per staged chunk
#define NCH (T_STEPS / CH)     // 16 chunks
#define ROWF (CH * 3)          // 24 floats per row per chunk
#define RSTRIDE (ROWF + 1)     // 25 (odd) -> conflict-free per-lane LDS reads
#define FPT 6                  // float4 loads/thread/chunk = 256*24/(4*256)

#define LOG2E 1.44269504088896f

typedef __attribute__((ext_vector_type(2))) float f2;

__device__ __forceinline__ float fast_rcp(float x) {
    return __builtin_amdgcn_rcpf(x);
}
__device__ __forceinline__ float fast_exp2(float x) {
    return __builtin_amdgcn_exp2f(x);
}

__global__ __launch_bounds__(BLOCK, 4) void lstm_nll_main(
    const float* __restrict__ x,       // (B, T, 3)
    const float* __restrict__ h0,      // (B)
    const float* __restrict__ c0,      // (B)
    const float* __restrict__ target,  // (B, 3)
    const float* __restrict__ W_ih,    // (4,3)
    const float* __restrict__ W_hh,    // (4,1)
    const float* __restrict__ b_ih,    // (4)
    const float* __restrict__ b_hh,    // (4)
    const float* __restrict__ W_mean,  // (3,128)
    const float* __restrict__ b_mean,  // (3)
    const float* __restrict__ W_var,   // (6,128)
    const float* __restrict__ b_var,   // (6)
    float* __restrict__ partial)       // (NBLOCKS)
{
    __shared__ float  lds_x[BLOCK * RSTRIDE];   // 25600 B
    __shared__ float4 wpack4[T_STEPS * 3];      // 6144 B
    __shared__ float  wavesum[BLOCK / 64];

    const int tid = threadIdx.x;

    // pack projection weights: per t: {m0,m1,m2,e0},{e1,e2,e3,e4},{e5,0,0,0}
    for (int idx = tid; idx < T_STEPS * 3; idx += BLOCK) {
        const int t = idx / 3;
        const int k = idx - t * 3;
        float4 v;
        if (k == 0)      v = make_float4(W_mean[0*T_STEPS+t], W_mean[1*T_STEPS+t],
                                         W_mean[2*T_STEPS+t], W_var[0*T_STEPS+t]);
        else if (k == 1) v = make_float4(W_var[1*T_STEPS+t], W_var[2*T_STEPS+t],
                                         W_var[3*T_STEPS+t], W_var[4*T_STEPS+t]);
        else             v = make_float4(W_var[5*T_STEPS+t], 0.f, 0.f, 0.f);
        wpack4[idx] = v;
    }

    const int b = blockIdx.x * BLOCK + tid;
    const float* xb = x + (size_t)b * (T_STEPS * 3);

    // hoist epilogue-only loads so their latency overlaps the whole kernel
    const float t0 = target[b*3+0], t1 = target[b*3+1], t2 = target[b*3+2];

    // ---- rotation from rows 127,126,125 ----
    const float v1x = xb[127*3+0], v1y = xb[127*3+1], v1z = xb[127*3+2];
    const float v2x = xb[126*3+0], v2y = xb[126*3+1], v2z = xb[126*3+2];
    const float v3x = xb[125*3+0], v3y = xb[125*3+1], v3z = xb[125*3+2];

    const float inv1 = rsqrtf(v1x*v1x + v1y*v1y + v1z*v1z);
    const float b1x = v1x*inv1, b1y = v1y*inv1, b1z = v1z*inv1;
    const float dp  = v2x*b1x + v2y*b1y + v2z*b1z;
    const float a2x = v2x - dp*b1x, a2y = v2y - dp*b1y, a2z = v2z - dp*b1z;
    const float inv2 = rsqrtf(a2x*a2x + a2y*a2y + a2z*a2z);
    const float b2x = a2x*inv2, b2y = a2y*inv2, b2z = a2z*inv2;
    float b3x = b1y*b2z - b1z*b2y;
    float b3y = b1z*b2x - b1x*b2z;
    float b3z = b1x*b2y - b1y*b2x;
    const float sgn = (v3x*b3x + v3y*b3y + v3z*b3z) > 0.0f ? 1.0f : -1.0f;
    b3x *= sgn; b3y *= sgn; b3z *= sgn;

    // ---- gate weights folded with rotation AND with -log2e scaling ----
    // gate order in f2 pairs: gA = (i, f), gB = (g, o)
    // scale: i,f,o by -log2e ; g by -2*log2e  (so exp2(arg) = e^{-gate} / e^{-2g})
    const float wi00 = W_ih[0], wi01 = W_ih[1],  wi02 = W_ih[2];
    const float wi10 = W_ih[3], wi11 = W_ih[4],  wi12 = W_ih[5];
    const float wi20 = W_ih[6], wi21 = W_ih[7],  wi22 = W_ih[8];
    const float wi30 = W_ih[9], wi31 = W_ih[10], wi32 = W_ih[11];
    const float s1 = -LOG2E, s2 = -2.0f * LOG2E;

    const f2 wAx = { s1*(wi00*b1x + wi01*b2x + wi02*b3x),
                     s1*(wi10*b1x + wi11*b2x + wi12*b3x) };
    const f2 wAy = { s1*(wi00*b1y + wi01*b2y + wi02*b3y),
                     s1*(wi10*b1y + wi11*b2y + wi12*b3y) };
    const f2 wAz = { s1*(wi00*b1z + wi01*b2z + wi02*b3z),
                     s1*(wi10*b1z + wi11*b2z + wi12*b3z) };
    const f2 wBx = { s2*(wi20*b1x + wi21*b2x + wi22*b3x),
                     s1*(wi30*b1x + wi31*b2x + wi32*b3x) };
    const f2 wBy = { s2*(wi20*b1y + wi21*b2y + wi22*b3y),
                     s1*(wi30*b1y + wi31*b2y + wi32*b3y) };
    const f2 wBz = { s2*(wi20*b1z + wi21*b2z + wi22*b3z),
                     s1*(wi30*b1z + wi31*b2z + wi32*b3z) };
    const f2 wAh = { s1*W_hh[0], s1*W_hh[1] };
    const f2 wBh = { s2*W_hh[2], s1*W_hh[3] };
    const f2 bgA = { s1*(b_ih[0] + b_hh[0]), s1*(b_ih[1] + b_hh[1]) };
    const f2 bgB = { s2*(b_ih[2] + b_hh[2]), s1*(b_ih[3] + b_hh[3]) };

    float h = h0[b];
    float c = c0[b];
    f2 P0 = {0.f, 0.f}, P1 = {0.f, 0.f}, P2 = {0.f, 0.f}, P3 = {0.f, 0.f};
    float e5a = 0.f;

    // ---- coalesced staging plan ----
    const float4* xg4 = (const float4*)(x + (size_t)blockIdx.x * BLOCK * (T_STEPS * 3));
    int ldsaddr[FPT];
    int gidx[FPT];
    #pragma unroll
    for (int j = 0; j < FPT; ++j) {
        const int f = j * BLOCK + tid;
        const int r = f / FPT;
        const int cc = f - r * FPT;
        ldsaddr[j] = r * RSTRIDE + cc * 4;
        gidx[j]    = r * (T_STEPS * 3 / 4) + cc;
    }

    float4 pre[FPT];
    #pragma unroll
    for (int j = 0; j < FPT; ++j) pre[j] = xg4[gidx[j]];

    const float* rowp = &lds_x[tid * RSTRIDE];

    for (int tc = 0; tc < NCH; ++tc) {
        __syncthreads();
        #pragma unroll
        for (int j = 0; j < FPT; ++j) {
            lds_x[ldsaddr[j] + 0] = pre[j].x;
            lds_x[ldsaddr[j] + 1] = pre[j].y;
            lds_x[ldsaddr[j] + 2] = pre[j].z;
            lds_x[ldsaddr[j] + 3] = pre[j].w;
        }
        __syncthreads();
        if (tc + 1 < NCH) {
            const int cb = (tc + 1) * FPT;
            #pragma unroll
            for (int j = 0; j < FPT; ++j) pre[j] = xg4[gidx[j] + cb];
        }

        // ---- phase A: serial recurrence, h into registers ----
        float hbuf[CH];
        #pragma unroll
        for (int s = 0; s < CH; ++s) {
            const f2 X = { rowp[s*3+0], rowp[s*3+0] };
            const f2 Y = { rowp[s*3+1], rowp[s*3+1] };
            const f2 Z = { rowp[s*3+2], rowp[s*3+2] };
            const f2 H = { h, h };
            const f2 gA = wAx*X + wAy*Y + wAz*Z + wAh*H + bgA;  // (i,f) scaled
            const f2 gB = wBx*X + wBy*Y + wBz*Z + wBh*H + bgB;  // (g,o) scaled
            const float u = fast_exp2(gA.x);   // e^{-gi}
            const float a = fast_exp2(gA.y);   // e^{-gf}
            const float v = fast_exp2(gB.x);   // e^{-2gg}
            const float z = fast_exp2(gB.y);   // e^{-go}
            // c' = [c(1+u)(1+v) + (1-v)(1+a)] / [(1+a)(1+u)(1+v)]
            const float U = 1.0f + u, A = 1.0f + a, V = 1.0f + v;
            const float Q = U * V;
            const float num = __builtin_fmaf(c, Q, (2.0f - V) * A);
            const float den = Q * A;
            c = num * fast_rcp(den);
            // h = (1-w)/[(1+z)(1+w)], w = e^{-2c}, clamp exp2 arg for safety
            const float wm_raw = c * (-2.0f * LOG2E);
            const float wm = fminf(fmaxf(wm_raw, -126.0f), 126.0f);
            const float w = fast_exp2(wm);
            const float W = 1.0f + w;
            h = (2.0f - W) * fast_rcp((1.0f + z) * W);
            hbuf[s] = h;
        }
        // ---- phase B: streaming projection accumulate (packed) ----
        #pragma unroll
        for (int s = 0; s < CH; ++s) {
            const int t = tc * CH + s;
            const float4 w0 = wpack4[t*3+0];
            const float4 w1 = wpack4[t*3+1];
            const float4 w2 = wpack4[t*3+2];
            const float hv = hbuf[s];
            const f2 Hv = { hv, hv };
            P0 += ((f2){w0.x, w0.y}) * Hv;
            P1 += ((f2){w0.z, w0.w}) * Hv;
            P2 += ((f2){w1.x, w1.y}) * Hv;
            P3 += ((f2){w1.z, w1.w}) * Hv;
            e5a += w2.x * hv;
        }
    }

    // ---- epilogue: NLL (division-free) ----
    const float m0 = P0.x + b_mean[0];
    const float m1 = P0.y + b_mean[1];
    const float m2 = P1.x + b_mean[2];
    const float e0 = P1.y + b_var[0];
    const float e1 = P2.x + b_var[1];
    const float e2 = P2.y + b_var[2];
    const float e3 = P3.x + b_var[3];
    const float e4 = P3.y + b_var[4];
    const float e5 = e5a  + b_var[5];

    const float dv0 = fast_exp2(e3 * LOG2E);
    const float dv1 = fast_exp2(e4 * LOG2E);
    const float dv2 = fast_exp2(e5 * LOG2E);

    const float rt0 = b1x*t0 + b1y*t1 + b1z*t2;
    const float rt1 = b2x*t0 + b2y*t1 + b2z*t2;
    const float rt2 = b3x*t0 + b3y*t1 + b3z*t2;

    const float d0 = m0 - rt0, d1 = m1 - rt1, d2 = m2 - rt2;
    const float y0 = d0;
    const float y1 = d1 - e0 * y0;
    const float y2 = d2 - e1 * y0 - e2 * y1;
    const float quad = y0*y0*fast_rcp(dv0) + y1*y1*fast_rcp(dv1)
                     + y2*y2*fast_rcp(dv2);

    float contrib = 0.5f * (dv0 + dv1 + dv2) + 0.5f * quad;

    #pragma unroll
    for (int off = 32; off > 0; off >>= 1)
        contrib += __shfl_down(contrib, off, 64);
    const int lane = tid & 63, wid = tid >> 6;
    if (lane == 0) wavesum[wid] = contrib;
    __syncthreads();
    if (tid == 0) {
        float s = 0.f;
        #pragma unroll
        for (int w = 0; w < BLOCK / 64; ++w) s += wavesum[w];
        partial[blockIdx.x] = s;
    }
}

__global__ __launch_bounds__(256) void lstm_nll_finalize(
    const float* __restrict__ partial, float* __restrict__ out, int n)
{
    const int tid = threadIdx.x;
    float s = (tid < n) ? partial[tid] : 0.0f;
    #pragma unroll
    for (int off = 32; off > 0; off >>= 1)
        s += __shfl_down(s, off, 64);
    __shared__ float wavesum[4];
    const int lane = tid & 63, wid = tid >> 6;
    if (lane == 0) wavesum[wid] = s;
    __syncthreads();
    if (tid == 0) {
        out[0] = (wavesum[0] + wavesum[1] + wavesum[2] + wavesum[3]) *
                 (1.0f / (float)B_TOTAL);
    }
}

extern "C" void kernel_launch(void* const* d_in, const int* in_sizes, int n_in,
                              void* d_out, int out_size, void* d_ws, size_t ws_size,
                              hipStream_t stream) {
    const float* x      = (const float*)d_in[0];
    const float* h0     = (const float*)d_in[1];
    const float* c0     = (const float*)d_in[2];
    const float* target = (const float*)d_in[3];
    const float* W_ih   = (const float*)d_in[4];
    const float* W_hh   = (const float*)d_in[5];
    const float* b_ih   = (const float*)d_in[6];
    const float* b_hh   = (const float*)d_in[7];
    const float* W_mean = (const float*)d_in[8];
    const float* b_mean = (const float*)d_in[9];
    const float* W_var  = (const float*)d_in[10];
    const float* b_var  = (const float*)d_in[11];

    float* partial = (float*)d_ws;

    lstm_nll_main<<<NBLOCKS, BLOCK, 0, stream>>>(
        x, h0, c0, target, W_ih, W_hh, b_ih, b_hh,
        W_mean, b_mean, W_var, b_var, partial);
    lstm_nll_finalize<<<1, 256, 0, stream>>>(partial, (float*)d_out, NBLOCKS);
}